// Round 1
// baseline (2064.786 us; speedup 1.0000x reference)
//
#include <hip/hip_runtime.h>

#define D_FEAT 128
#define C1 64
#define C2 32

// Tiled SGEMM for tall-skinny C = act(A[N][K]) @ W[K][NO], NO in {64,32}.
// W is tiny (<=32KB) -> staged whole in LDS. A staged in 64-row x 64-k tiles.
template<int K, int NO, bool RELU_IN>
__global__ __launch_bounds__(256) void gemm_small_w(const float* __restrict__ A,
                                                    const float* __restrict__ W,
                                                    float* __restrict__ C, int n) {
    constexpr int BM = 64;            // rows per block
    constexpr int KT = 64;            // k-tile
    constexpr int KP = KT + 4;        // padded LDS stride (breaks bank aliasing)
    constexpr int TC = NO / 4;        // col-groups (4 cols each, float4)
    constexpr int TR = 256 / TC;      // row-groups
    constexpr int RPT = BM / TR;      // rows per thread

    __shared__ float ws[K * NO];
    __shared__ float xs[BM * KP];

    const int t = threadIdx.x;
    const int row0 = blockIdx.x * BM;

    // stage all of W (row-major [K][NO])
    for (int i = t; i < K * NO / 4; i += 256)
        ((float4*)ws)[i] = ((const float4*)W)[i];

    const int cg = t % TC;            // col group -> cols cg*4 .. cg*4+3
    const int rg = t / TC;            // row group -> rows rg*RPT .. +RPT-1

    float acc[RPT][4];
    #pragma unroll
    for (int i = 0; i < RPT; i++)
        for (int j = 0; j < 4; j++) acc[i][j] = 0.f;

    for (int kt = 0; kt < K; kt += KT) {
        __syncthreads();              // protect xs from previous iter readers
        // stage A tile [BM][KT] (apply relu on input if requested)
        for (int i = t; i < BM * KT / 4; i += 256) {
            int r  = i / (KT / 4);
            int kc = i % (KT / 4);
            float4 v = make_float4(0.f, 0.f, 0.f, 0.f);
            if (row0 + r < n)
                v = *(const float4*)(A + (size_t)(row0 + r) * K + kt + kc * 4);
            if (RELU_IN) {
                v.x = fmaxf(v.x, 0.f); v.y = fmaxf(v.y, 0.f);
                v.z = fmaxf(v.z, 0.f); v.w = fmaxf(v.w, 0.f);
            }
            *(float4*)(xs + r * KP + kc * 4) = v;
        }
        __syncthreads();

        #pragma unroll
        for (int k = 0; k < KT; k += 4) {
            float4 wv[4];
            #pragma unroll
            for (int kk = 0; kk < 4; kk++)
                wv[kk] = *(const float4*)(ws + (kt + k + kk) * NO + cg * 4);
            #pragma unroll
            for (int i = 0; i < RPT; i++) {
                const int r = rg * RPT + i;
                float4 xv = *(const float4*)(xs + r * KP + k);
                const float xk[4] = {xv.x, xv.y, xv.z, xv.w};
                #pragma unroll
                for (int kk = 0; kk < 4; kk++) {
                    acc[i][0] += xk[kk] * wv[kk].x;
                    acc[i][1] += xk[kk] * wv[kk].y;
                    acc[i][2] += xk[kk] * wv[kk].z;
                    acc[i][3] += xk[kk] * wv[kk].w;
                }
            }
        }
    }

    #pragma unroll
    for (int i = 0; i < RPT; i++) {
        const int r = row0 + rg * RPT + i;
        if (r < n)
            *(float4*)(C + (size_t)r * NO + cg * 4) =
                make_float4(acc[i][0], acc[i][1], acc[i][2], acc[i][3]);
    }
}

// OUT[row[e]] += val[e] * H[col[e]]   via float atomics.
// F/4 threads per edge, each handling a float4 feature chunk.
template<int F>
__global__ __launch_bounds__(256) void spmm_atomic(const int* __restrict__ row,
                                                   const int* __restrict__ col,
                                                   const float* __restrict__ val,
                                                   const float* __restrict__ H,
                                                   float* __restrict__ OUT, int E) {
    constexpr int TPE = F / 4;
    const long long tid = (long long)blockIdx.x * 256 + threadIdx.x;
    const int e = (int)(tid / TPE);
    const int c = (int)(tid % TPE);
    if (e >= E) return;
    const int r  = row[e];
    const int cl = col[e];
    const float v = val[e];
    const float4 h = ((const float4*)H)[(size_t)cl * TPE + c];
    float* o = OUT + (size_t)r * F + (size_t)c * 4;
    atomicAdd(o + 0, v * h.x);
    atomicAdd(o + 1, v * h.y);
    atomicAdd(o + 2, v * h.z);
    atomicAdd(o + 3, v * h.w);
}

extern "C" void kernel_launch(void* const* d_in, const int* in_sizes, int n_in,
                              void* d_out, int out_size, void* d_ws, size_t ws_size,
                              hipStream_t stream) {
    const float* x    = (const float*)d_in[0];
    const int*   erow = (const int*)d_in[1];
    const int*   ecol = (const int*)d_in[2];
    const float* eval = (const float*)d_in[3];
    const float* w1   = (const float*)d_in[4];
    const float* w2   = (const float*)d_in[5];
    float* out = (float*)d_out;

    const int n = in_sizes[0] / D_FEAT;   // 100000 nodes
    const int E = in_sizes[1];            // 1600000 edges

    float* y1 = (float*)d_ws;                       // [n][64]
    float* s1 = y1 + (size_t)n * C1;                // [n][64]
    float* z  = s1 + (size_t)n * C1;                // [n][32]

    // zero accumulation buffers (atomics accumulate into them)
    hipMemsetAsync(s1, 0, (size_t)n * C1 * sizeof(float), stream);
    hipMemsetAsync(d_out, 0, (size_t)out_size * sizeof(float), stream);

    // Layer 1: Y1 = X @ W1
    gemm_small_w<D_FEAT, C1, false><<<(n + 63) / 64, 256, 0, stream>>>(x, w1, y1, n);
    // S1 = A @ Y1
    {
        long long threads = (long long)E * (C1 / 4);
        int blocks = (int)((threads + 255) / 256);
        spmm_atomic<C1><<<blocks, 256, 0, stream>>>(erow, ecol, eval, y1, s1, E);
    }
    // Layer 2: Z = relu(S1) @ W2
    gemm_small_w<C1, C2, true><<<(n + 63) / 64, 256, 0, stream>>>(s1, w2, z, n);
    // out = A @ Z
    {
        long long threads = (long long)E * (C2 / 4);
        int blocks = (int)((threads + 255) / 256);
        spmm_atomic<C2><<<blocks, 256, 0, stream>>>(erow, ecol, eval, z, out, E);
    }
}

// Round 2
// 425.369 us; speedup vs baseline: 4.8541x; 4.8541x over previous
//
#include <hip/hip_runtime.h>

#define D_FEAT 128
#define C1 64
#define C2 32
#define SCAN_B 256

// ---------------- GEMM: C = act(A[N][K]) @ W[K][NO], W tiny -> whole in LDS ----
template<int K, int NO, bool RELU_IN>
__global__ __launch_bounds__(256) void gemm_small_w(const float* __restrict__ A,
                                                    const float* __restrict__ W,
                                                    float* __restrict__ C, int n) {
    constexpr int BM = 64;
    constexpr int KT = 64;
    constexpr int KP = KT + 4;
    constexpr int TC = NO / 4;
    constexpr int TR = 256 / TC;
    constexpr int RPT = BM / TR;

    __shared__ float ws[K * NO];
    __shared__ float xs[BM * KP];

    const int t = threadIdx.x;
    const int row0 = blockIdx.x * BM;

    for (int i = t; i < K * NO / 4; i += 256)
        ((float4*)ws)[i] = ((const float4*)W)[i];

    const int cg = t % TC;
    const int rg = t / TC;

    float acc[RPT][4];
    #pragma unroll
    for (int i = 0; i < RPT; i++)
        for (int j = 0; j < 4; j++) acc[i][j] = 0.f;

    for (int kt = 0; kt < K; kt += KT) {
        __syncthreads();
        for (int i = t; i < BM * KT / 4; i += 256) {
            int r  = i / (KT / 4);
            int kc = i % (KT / 4);
            float4 v = make_float4(0.f, 0.f, 0.f, 0.f);
            if (row0 + r < n)
                v = *(const float4*)(A + (size_t)(row0 + r) * K + kt + kc * 4);
            if (RELU_IN) {
                v.x = fmaxf(v.x, 0.f); v.y = fmaxf(v.y, 0.f);
                v.z = fmaxf(v.z, 0.f); v.w = fmaxf(v.w, 0.f);
            }
            *(float4*)(xs + r * KP + kc * 4) = v;
        }
        __syncthreads();

        #pragma unroll
        for (int k = 0; k < KT; k += 4) {
            float4 wv[4];
            #pragma unroll
            for (int kk = 0; kk < 4; kk++)
                wv[kk] = *(const float4*)(ws + (kt + k + kk) * NO + cg * 4);
            #pragma unroll
            for (int i = 0; i < RPT; i++) {
                const int r = rg * RPT + i;
                float4 xv = *(const float4*)(xs + r * KP + k);
                const float xk[4] = {xv.x, xv.y, xv.z, xv.w};
                #pragma unroll
                for (int kk = 0; kk < 4; kk++) {
                    acc[i][0] += xk[kk] * wv[kk].x;
                    acc[i][1] += xk[kk] * wv[kk].y;
                    acc[i][2] += xk[kk] * wv[kk].z;
                    acc[i][3] += xk[kk] * wv[kk].w;
                }
            }
        }
    }

    #pragma unroll
    for (int i = 0; i < RPT; i++) {
        const int r = row0 + rg * RPT + i;
        if (r < n)
            *(float4*)(C + (size_t)r * NO + cg * 4) =
                make_float4(acc[i][0], acc[i][1], acc[i][2], acc[i][3]);
    }
}

// ---------------- CSR build -------------------------------------------------
__global__ __launch_bounds__(256) void hist_kernel(const int* __restrict__ row,
                                                   int* __restrict__ deg, int E) {
    int i = blockIdx.x * 256 + threadIdx.x;
    if (i < E) atomicAdd(&deg[row[i]], 1);
}

__global__ __launch_bounds__(SCAN_B) void scan_block(const int* __restrict__ deg,
                                                     int* __restrict__ ptr,
                                                     int* __restrict__ sums, int n) {
    __shared__ int s[SCAN_B];
    int i = blockIdx.x * SCAN_B + threadIdx.x;
    int v = (i < n) ? deg[i] : 0;
    s[threadIdx.x] = v;
    __syncthreads();
    for (int off = 1; off < SCAN_B; off <<= 1) {
        int t = (threadIdx.x >= off) ? s[threadIdx.x - off] : 0;
        __syncthreads();
        s[threadIdx.x] += t;
        __syncthreads();
    }
    if (i < n) ptr[i] = s[threadIdx.x] - v;          // exclusive scan
    if (threadIdx.x == SCAN_B - 1) sums[blockIdx.x] = s[SCAN_B - 1];
}

__global__ __launch_bounds__(1024) void scan_sums(int* __restrict__ sums, int nb) {
    __shared__ int s[1024];
    int v = (threadIdx.x < nb) ? sums[threadIdx.x] : 0;
    s[threadIdx.x] = v;
    __syncthreads();
    for (int off = 1; off < 1024; off <<= 1) {
        int t = (threadIdx.x >= off) ? s[threadIdx.x - off] : 0;
        __syncthreads();
        s[threadIdx.x] += t;
        __syncthreads();
    }
    if (threadIdx.x < nb) sums[threadIdx.x] = s[threadIdx.x] - v;  // exclusive
}

__global__ __launch_bounds__(SCAN_B) void scan_add(int* __restrict__ ptr,
                                                   const int* __restrict__ sums, int n) {
    int i = blockIdx.x * SCAN_B + threadIdx.x;
    if (i < n) ptr[i] += sums[blockIdx.x];
}

// fill: ptr holds exclusive row starts; mutated to inclusive row ends.
__global__ __launch_bounds__(256) void fill_kernel(const int* __restrict__ row,
                                                   const int* __restrict__ col,
                                                   const float* __restrict__ val,
                                                   int* __restrict__ ptr,
                                                   int* __restrict__ csr_col,
                                                   float* __restrict__ csr_val, int E) {
    int i = blockIdx.x * 256 + threadIdx.x;
    if (i >= E) return;
    int r = row[i];
    int pos = atomicAdd(&ptr[r], 1);
    csr_col[pos] = col[i];
    csr_val[pos] = val[i];
}

// ---------------- SpMM via CSR gather: one wave per row ----------------------
// ptr_end[i] = inclusive end of row i; start = (i==0 ? 0 : ptr_end[i-1]).
__global__ __launch_bounds__(256) void spmm_csr64(const int* __restrict__ ptr_end,
                                                  const int* __restrict__ cols,
                                                  const float* __restrict__ vals,
                                                  const float* __restrict__ H,
                                                  float* __restrict__ OUT, int n) {
    const int wid  = (blockIdx.x * 256 + threadIdx.x) >> 6;
    const int lane = threadIdx.x & 63;
    if (wid >= n) return;
    const int start = (wid == 0) ? 0 : ptr_end[wid - 1];
    const int end   = ptr_end[wid];
    float acc = 0.f;
    int e = start;
    for (; e + 1 < end; e += 2) {
        int   c0 = cols[e],  c1 = cols[e + 1];
        float v0 = vals[e],  v1 = vals[e + 1];
        float h0 = H[(size_t)c0 * C1 + lane];
        float h1 = H[(size_t)c1 * C1 + lane];
        acc += v0 * h0 + v1 * h1;
    }
    if (e < end)
        acc += vals[e] * H[(size_t)cols[e] * C1 + lane];
    OUT[(size_t)wid * C1 + lane] = acc;
}

__global__ __launch_bounds__(256) void spmm_csr32(const int* __restrict__ ptr_end,
                                                  const int* __restrict__ cols,
                                                  const float* __restrict__ vals,
                                                  const float* __restrict__ H,
                                                  float* __restrict__ OUT, int n) {
    const int wid  = (blockIdx.x * 256 + threadIdx.x) >> 6;
    const int lane = threadIdx.x & 63;
    if (wid >= n) return;
    const int half = lane >> 5;         // 0/1 -> processes edges start+half, step 2
    const int f    = lane & 31;
    const int start = (wid == 0) ? 0 : ptr_end[wid - 1];
    const int end   = ptr_end[wid];
    float acc = 0.f;
    for (int e = start + half; e < end; e += 2)
        acc += vals[e] * H[(size_t)cols[e] * C2 + f];
    acc += __shfl_xor(acc, 32, 64);
    if (half == 0)
        OUT[(size_t)wid * C2 + f] = acc;
}

// ---------------- launcher ---------------------------------------------------
extern "C" void kernel_launch(void* const* d_in, const int* in_sizes, int n_in,
                              void* d_out, int out_size, void* d_ws, size_t ws_size,
                              hipStream_t stream) {
    const float* x    = (const float*)d_in[0];
    const int*   erow = (const int*)d_in[1];
    const int*   ecol = (const int*)d_in[2];
    const float* eval = (const float*)d_in[3];
    const float* w1   = (const float*)d_in[4];
    const float* w2   = (const float*)d_in[5];
    float* out = (float*)d_out;

    const int n = in_sizes[0] / D_FEAT;   // 100000
    const int E = in_sizes[1];            // 1600000

    // workspace layout (bytes): y1 | s1 | csr_col | csr_val | deg | ptr | sums
    float* y1      = (float*)d_ws;                          // [n][64]
    float* s1      = y1 + (size_t)n * C1;                   // [n][64]
    int*   csr_col = (int*)(s1 + (size_t)n * C1);           // [E]
    float* csr_val = (float*)(csr_col + E);                 // [E]
    int*   deg     = (int*)(csr_val + E);                   // [n]
    int*   ptr     = deg + n;                               // [n]
    int*   sums    = ptr + n;                               // [ceil(n/256)]
    float* z       = y1;                                    // [n][32] aliases y1 (dead by then)

    const int nb = (n + SCAN_B - 1) / SCAN_B;
    const int eb = (E + 255) / 256;

    // ---- CSR build ----
    hipMemsetAsync(deg, 0, (size_t)n * sizeof(int), stream);
    hist_kernel<<<eb, 256, 0, stream>>>(erow, deg, E);
    scan_block<<<nb, SCAN_B, 0, stream>>>(deg, ptr, sums, n);
    scan_sums<<<1, 1024, 0, stream>>>(sums, nb);
    scan_add<<<nb, SCAN_B, 0, stream>>>(ptr, sums, n);
    fill_kernel<<<eb, 256, 0, stream>>>(erow, ecol, eval, ptr, csr_col, csr_val, E);
    // ptr now holds inclusive row ends.

    // ---- Layer 1 ----
    gemm_small_w<D_FEAT, C1, false><<<(n + 63) / 64, 256, 0, stream>>>(x, w1, y1, n);
    spmm_csr64<<<(n + 3) / 4, 256, 0, stream>>>(ptr, csr_col, csr_val, y1, s1, n);

    // ---- Layer 2 ----
    gemm_small_w<C1, C2, true><<<(n + 63) / 64, 256, 0, stream>>>(s1, w2, z, n);
    spmm_csr32<<<(n + 3) / 4, 256, 0, stream>>>(ptr, csr_col, csr_val, z, out, n);
}